// Round 8
// baseline (46.445 us; speedup 1.0000x reference)
//
#include <hip/hip_runtime.h>
#include <hip/hip_bf16.h>

#define NPOS (4*16*64*64)             // 262144 positions
#define KCODES 512
#define CDIM 64
#define OUT_SCALAR_IDX ((size_t)NPOS * CDIM)

// d_ws layout
#define WS_GCOUNT 0                   // 512 * int (used-flags)
#define WS_EMB    4096                // 32 KB: fp8 image of (-512*e), k-interleaved rows
#define WS_EE     (4096 + 32768)      // 512 * float: 256*(1 + ||e||^2)

typedef float f32x4 __attribute__((ext_vector_type(4)));
typedef long lng2 __attribute__((ext_vector_type(2)));

// ---- prep: codebook -> fp8 image + biased/scaled ee + zero flags ----
// Row r (64 B): byte [kg*16 + h*8 + j] = fp8(-512 * e[r][h*32 + kg*8 + j])
// so a lane's 16B read at kg*16 yields both K=32 fragment halves contiguously.
__global__ __launch_bounds__(64) void vq_prep(
    const float* __restrict__ emb, char* __restrict__ ws) {
  const int r = blockIdx.x * 64 + threadIdx.x;     // 8 x 64 = 512 rows
  ((int*)(ws + WS_GCOUNT))[r] = 0;
  float c[CDIM];
  float ee = 0.f;
  #pragma unroll
  for (int q = 0; q < 16; ++q) {
    float4 x = ((const float4*)(emb + r * CDIM))[q];
    c[4*q+0] = x.x; c[4*q+1] = x.y; c[4*q+2] = x.z; c[4*q+3] = x.w;
    ee = fmaf(x.x, x.x, ee); ee = fmaf(x.y, x.y, ee);
    ee = fmaf(x.z, x.z, ee); ee = fmaf(x.w, x.w, ee);
  }
  uint u[16];
  #pragma unroll
  for (int kg = 0; kg < 4; ++kg)
    #pragma unroll
    for (int h = 0; h < 2; ++h)
      #pragma unroll
      for (int jj = 0; jj < 2; ++jj) {
        const int kb = h * 32 + kg * 8 + jj * 4;
        uint p = __builtin_amdgcn_cvt_pk_fp8_f32(-512.f * c[kb+0], -512.f * c[kb+1], 0u, false);
        p = __builtin_amdgcn_cvt_pk_fp8_f32(-512.f * c[kb+2], -512.f * c[kb+3], p, true);
        u[kg * 4 + h * 2 + jj] = p;
      }
  uint4* img = (uint4*)(ws + WS_EMB + r * 64);
  img[0] = make_uint4(u[0], u[1], u[2], u[3]);
  img[1] = make_uint4(u[4], u[5], u[6], u[7]);
  img[2] = make_uint4(u[8], u[9], u[10], u[11]);
  img[3] = make_uint4(u[12], u[13], u[14], u[15]);
  ((float*)(ws + WS_EE))[r] = 256.f * (1.f + ee);  // bias -> acc ~256, uint-monotone
}

__global__ __launch_bounds__(512, 8) void vq_mfma(
    const float* __restrict__ z, const float* __restrict__ emb,
    const char* __restrict__ ws, float* __restrict__ out,
    int* __restrict__ gflags) {
  __shared__ lng2 embs[2048];              // 32 KB fp8 image (16B-aligned)
  __shared__ float s_ee[KCODES];           // 2 KB
  __shared__ uint s_idx[256];              // 1 KB
  __shared__ int s_hist[KCODES];           // 2 KB

  const int tid = threadIdx.x;
  const int lane = tid & 63;
  const int w = tid >> 6;                  // 8 waves, 32 positions each
  const int col = lane & 15;
  const int kg = lane >> 4;

  // ---- async DMA: image + ee -> LDS ----
  if (tid < 128)
    __builtin_amdgcn_global_load_lds(
        (const __attribute__((address_space(1))) void*)(ws + WS_EE + tid * 16),
        (__attribute__((address_space(3))) void*)((char*)s_ee + tid * 16), 16, 0, 0);
  const char* src = ws + WS_EMB;
  #pragma unroll
  for (int i = 0; i < 4; ++i) {
    const int off = (i * 512 + tid) * 16;
    __builtin_amdgcn_global_load_lds(
        (const __attribute__((address_space(1))) void*)(src + off),
        (__attribute__((address_space(3))) void*)((char*)embs + off), 16, 0, 0);
  }

  // ---- A fragments: 2 row-tiles x 2 K-halves, fp8 (loads overlap DMA) ----
  const int nb = blockIdx.x * 256;
  const int b = nb >> 16, spb = nb & 65535;     // 256 | 65536 -> single batch
  const float* zp0 = z + ((size_t)b << 22) + spb;
  long af[2][2];
  #pragma unroll
  for (int rt = 0; rt < 2; ++rt) {
    const float* zp = zp0 + w * 32 + rt * 16 + col;
    #pragma unroll
    for (int h = 0; h < 2; ++h) {
      float v[8];
      #pragma unroll
      for (int j = 0; j < 8; ++j)
        v[j] = zp[(size_t)(h * 32 + kg * 8 + j) << 16];
      uint u0 = __builtin_amdgcn_cvt_pk_fp8_f32(v[0], v[1], 0u, false);
      u0 = __builtin_amdgcn_cvt_pk_fp8_f32(v[2], v[3], u0, true);
      uint u1 = __builtin_amdgcn_cvt_pk_fp8_f32(v[4], v[5], 0u, false);
      u1 = __builtin_amdgcn_cvt_pk_fp8_f32(v[6], v[7], u1, true);
      af[rt][h] = ((long)u1 << 32) | (long)u0;
    }
  }
  s_hist[tid] = 0;

  __syncthreads();   // drains DMA + hist zero

  // ---- hot loop: 32 code-tiles; acc = 256*(1+ee-2ze) directly ----
  uint key[2][4];
  #pragma unroll
  for (int rt = 0; rt < 2; ++rt)
    #pragma unroll
    for (int s = 0; s < 4; ++s) key[rt][s] = 0xFFFFFFFFu;

  const int lbyte = col * 64 + kg * 16;

  lng2 bb = *(const lng2*)((const char*)embs + lbyte);
  float eev = s_ee[col];

  #pragma unroll 8
  for (int ct = 0; ct < 32; ++ct) {
    const lng2 bc = bb;
    const float ec = eev;
    const uint ctv = (uint)ct;
    const int nct = (ct + 1) & 31;                 // wrap: harmless reload
    bb = *(const lng2*)((const char*)embs + nct * 1024 + lbyte);
    eev = s_ee[nct * 16 + col];
    const f32x4 cin = {ec, ec, ec, ec};
    #pragma unroll
    for (int rt = 0; rt < 2; ++rt) {
      f32x4 acc = __builtin_amdgcn_mfma_f32_16x16x32_fp8_fp8(af[rt][0], bc.x, cin, 0, 0, 0);
      acc = __builtin_amdgcn_mfma_f32_16x16x32_fp8_fp8(af[rt][1], bc.y, acc, 0, 0, 0);
      #pragma unroll
      for (int s = 0; s < 4; ++s) {
        uint kb = (__builtin_bit_cast(uint, acc[s]) & 0xFFFFFFE0u) | ctv;
        key[rt][s] = kb < key[rt][s] ? kb : key[rt][s];
      }
    }
  }

  // ---- per-row argmin across 16 cols: pure uint-min butterfly ----
  #pragma unroll
  for (int rt = 0; rt < 2; ++rt) {
    #pragma unroll
    for (int s = 0; s < 4; ++s) {
      uint k = (key[rt][s] << 4) | (uint)col;   // (dist, ct, col) lex order
      #pragma unroll
      for (int m = 1; m < 16; m <<= 1) {
        uint o = (uint)__shfl_xor((int)k, m, 64);
        k = o < k ? o : k;
      }
      if (col == 0) s_idx[w * 32 + rt * 16 + kg * 4 + s] = k;
    }
  }
  __syncthreads();

  // ---- epilogue: 2 threads per position; exact fp32 gather + coalesced write ----
  const int p = tid & 255;
  const int half = tid >> 8;                 // channels [half*32, half*32+32)
  const uint kk = s_idx[p];
  const int myidx = (int)(((kk >> 4) & 31u) * 16u + (kk & 15u));
  if (half == 0) atomicAdd(&s_hist[myidx], 1);
  {
    const float4* ef = (const float4*)(emb + myidx * CDIM + half * 32);
    float* o = out + ((size_t)b << 22) + ((size_t)(half * 32) << 16) + spb + p;
    #pragma unroll
    for (int q = 0; q < 8; ++q) {
      float4 e4 = ef[q];
      o[(size_t)(4 * q + 0) << 16] = e4.x;
      o[(size_t)(4 * q + 1) << 16] = e4.y;
      o[(size_t)(4 * q + 2) << 16] = e4.z;
      o[(size_t)(4 * q + 3) << 16] = e4.w;
    }
  }
  __syncthreads();
  if (s_hist[tid]) gflags[tid] = 1;          // idempotent used-flags (512 entries)
}

__global__ __launch_bounds__(512) void vq_count(
    const int* __restrict__ gflags, float* __restrict__ out) {
  __shared__ int red[512];
  const int t = threadIdx.x;
  red[t] = (gflags[t] > 0) ? 1 : 0;
  __syncthreads();
  for (int s = 256; s > 0; s >>= 1) {
    if (t < s) red[t] += red[t + s];
    __syncthreads();
  }
  if (t == 0) out[OUT_SCALAR_IDX] = (float)red[0];
}

extern "C" void kernel_launch(void* const* d_in, const int* in_sizes, int n_in,
                              void* d_out, int out_size, void* d_ws, size_t ws_size,
                              hipStream_t stream) {
  const float* z = (const float*)d_in[0];
  const float* emb = (const float*)d_in[1];
  float* out = (float*)d_out;
  char* ws = (char*)d_ws;
  int* gflags = (int*)(ws + WS_GCOUNT);

  vq_prep<<<8, 64, 0, stream>>>(emb, ws);
  vq_mfma<<<NPOS / 256, 512, 0, stream>>>(z, emb, ws, out, gflags);
  vq_count<<<1, 512, 0, stream>>>(gflags, out);
}

// Round 9
// 45.725 us; speedup vs baseline: 1.0157x; 1.0157x over previous
//
#include <hip/hip_runtime.h>
#include <hip/hip_bf16.h>

#define NPOS (4*16*64*64)             // 262144 positions
#define KCODES 512
#define CDIM 64
#define OUT_SCALAR_IDX ((size_t)NPOS * CDIM)

// d_ws layout
#define WS_GCOUNT 0                   // 512 * int (used-flags)
#define WS_EMB    4096                // 32 KB: fp8(-512*e), kg-major: [kg][code][16B]
#define WS_EE     (4096 + 32768)      // 512 * float: 256*(1 + ||e||^2)

typedef float f32x4 __attribute__((ext_vector_type(4)));
typedef long lng2 __attribute__((ext_vector_type(2)));

// ---- prep: codebook -> kg-major fp8 image + biased/scaled ee + zero flags ----
// Region kg (8 KB), code r, byte [h*8 + j] = fp8(-512 * e[r][h*32 + kg*8 + j])
// -> a lane's 16B read at kg*8192 + r*16 holds both K-halves; addr/16 mod 8 =
//    (r mod 8) -> 16-lane groups spread over all 8 bank-quads (2-way, free).
__global__ __launch_bounds__(64) void vq_prep(
    const float* __restrict__ emb, char* __restrict__ ws) {
  const int r = blockIdx.x * 64 + threadIdx.x;     // 8 x 64 = 512 rows
  ((int*)(ws + WS_GCOUNT))[r] = 0;
  float c[CDIM];
  float ee = 0.f;
  #pragma unroll
  for (int q = 0; q < 16; ++q) {
    float4 x = ((const float4*)(emb + r * CDIM))[q];
    c[4*q+0] = x.x; c[4*q+1] = x.y; c[4*q+2] = x.z; c[4*q+3] = x.w;
    ee = fmaf(x.x, x.x, ee); ee = fmaf(x.y, x.y, ee);
    ee = fmaf(x.z, x.z, ee); ee = fmaf(x.w, x.w, ee);
  }
  #pragma unroll
  for (int kg = 0; kg < 4; ++kg) {
    uint u[4];
    #pragma unroll
    for (int h = 0; h < 2; ++h)
      #pragma unroll
      for (int jj = 0; jj < 2; ++jj) {
        const int kb = h * 32 + kg * 8 + jj * 4;
        uint p = __builtin_amdgcn_cvt_pk_fp8_f32(-512.f * c[kb+0], -512.f * c[kb+1], 0u, false);
        p = __builtin_amdgcn_cvt_pk_fp8_f32(-512.f * c[kb+2], -512.f * c[kb+3], p, true);
        u[h * 2 + jj] = p;
      }
    *(uint4*)(ws + WS_EMB + kg * 8192 + r * 16) = make_uint4(u[0], u[1], u[2], u[3]);
  }
  ((float*)(ws + WS_EE))[r] = 256.f * (1.f + ee);  // bias -> acc ~256, uint-monotone
}

__global__ __launch_bounds__(512, 8) void vq_mfma(
    const float* __restrict__ z, const float* __restrict__ emb,
    const char* __restrict__ ws, float* __restrict__ out,
    int* __restrict__ gflags) {
  __shared__ lng2 embs[2048];              // 32 KB fp8 image (16B-aligned)
  __shared__ float s_ee[KCODES];           // 2 KB
  __shared__ uint s_idx[256];              // 1 KB
  __shared__ int s_hist[KCODES];           // 2 KB

  const int tid = threadIdx.x;
  const int lane = tid & 63;
  const int w = tid >> 6;                  // 8 waves, 32 positions each
  const int col = lane & 15;
  const int kg = lane >> 4;

  // ---- async DMA: image + ee -> LDS (layout-preserving linear copy) ----
  if (tid < 128)
    __builtin_amdgcn_global_load_lds(
        (const __attribute__((address_space(1))) void*)(ws + WS_EE + tid * 16),
        (__attribute__((address_space(3))) void*)((char*)s_ee + tid * 16), 16, 0, 0);
  const char* src = ws + WS_EMB;
  #pragma unroll
  for (int i = 0; i < 4; ++i) {
    const int off = (i * 512 + tid) * 16;
    __builtin_amdgcn_global_load_lds(
        (const __attribute__((address_space(1))) void*)(src + off),
        (__attribute__((address_space(3))) void*)((char*)embs + off), 16, 0, 0);
  }

  // ---- A fragments: 2 row-tiles x 2 K-halves, fp8 (loads overlap DMA) ----
  const int nb = blockIdx.x * 256;
  const int b = nb >> 16, spb = nb & 65535;     // 256 | 65536 -> single batch
  const float* zp0 = z + ((size_t)b << 22) + spb;
  long af[2][2];
  #pragma unroll
  for (int rt = 0; rt < 2; ++rt) {
    const float* zp = zp0 + w * 32 + rt * 16 + col;
    #pragma unroll
    for (int h = 0; h < 2; ++h) {
      float v[8];
      #pragma unroll
      for (int j = 0; j < 8; ++j)
        v[j] = zp[(size_t)(h * 32 + kg * 8 + j) << 16];
      uint u0 = __builtin_amdgcn_cvt_pk_fp8_f32(v[0], v[1], 0u, false);
      u0 = __builtin_amdgcn_cvt_pk_fp8_f32(v[2], v[3], u0, true);
      uint u1 = __builtin_amdgcn_cvt_pk_fp8_f32(v[4], v[5], 0u, false);
      u1 = __builtin_amdgcn_cvt_pk_fp8_f32(v[6], v[7], u1, true);
      af[rt][h] = ((long)u1 << 32) | (long)u0;
    }
  }
  s_hist[tid] = 0;

  __syncthreads();   // drains DMA + hist zero

  // ---- hot loop: 32 code-tiles; acc = 256*(1+ee-2ze) directly ----
  uint key[2][4];
  #pragma unroll
  for (int rt = 0; rt < 2; ++rt)
    #pragma unroll
    for (int s = 0; s < 4; ++s) key[rt][s] = 0xFFFFFFFFu;

  const int lbyte = kg * 8192 + col * 16;      // kg-major region base

  lng2 bb = *(const lng2*)((const char*)embs + lbyte);
  float eev = s_ee[col];

  #pragma unroll 8
  for (int ct = 0; ct < 32; ++ct) {
    const lng2 bc = bb;
    const float ec = eev;
    const uint ctv = (uint)ct;
    const int nct = (ct + 1) & 31;               // wrap: harmless reload
    bb = *(const lng2*)((const char*)embs + nct * 256 + lbyte);
    eev = s_ee[nct * 16 + col];
    const f32x4 cin = {ec, ec, ec, ec};
    #pragma unroll
    for (int rt = 0; rt < 2; ++rt) {
      f32x4 acc = __builtin_amdgcn_mfma_f32_16x16x32_fp8_fp8(af[rt][0], bc.x, cin, 0, 0, 0);
      acc = __builtin_amdgcn_mfma_f32_16x16x32_fp8_fp8(af[rt][1], bc.y, acc, 0, 0, 0);
      #pragma unroll
      for (int s = 0; s < 4; ++s) {
        uint kb = (__builtin_bit_cast(uint, acc[s]) & 0xFFFFFFE0u) | ctv;
        key[rt][s] = kb < key[rt][s] ? kb : key[rt][s];
      }
    }
  }

  // ---- per-row argmin across 16 cols: pure uint-min butterfly ----
  #pragma unroll
  for (int rt = 0; rt < 2; ++rt) {
    #pragma unroll
    for (int s = 0; s < 4; ++s) {
      uint k = (key[rt][s] << 4) | (uint)col;   // (dist, ct, col) lex order
      #pragma unroll
      for (int m = 1; m < 16; m <<= 1) {
        uint o = (uint)__shfl_xor((int)k, m, 64);
        k = o < k ? o : k;
      }
      if (col == 0) s_idx[w * 32 + rt * 16 + kg * 4 + s] = k;
    }
  }
  __syncthreads();

  // ---- epilogue: 2 threads per position; exact fp32 gather + coalesced write ----
  const int p = tid & 255;
  const int half = tid >> 8;                 // channels [half*32, half*32+32)
  const uint kk = s_idx[p];
  const int myidx = (int)(((kk >> 4) & 31u) * 16u + (kk & 15u));
  if (half == 0) atomicAdd(&s_hist[myidx], 1);
  {
    const float4* ef = (const float4*)(emb + myidx * CDIM + half * 32);
    float* o = out + ((size_t)b << 22) + ((size_t)(half * 32) << 16) + spb + p;
    #pragma unroll
    for (int q = 0; q < 8; ++q) {
      float4 e4 = ef[q];
      o[(size_t)(4 * q + 0) << 16] = e4.x;
      o[(size_t)(4 * q + 1) << 16] = e4.y;
      o[(size_t)(4 * q + 2) << 16] = e4.z;
      o[(size_t)(4 * q + 3) << 16] = e4.w;
    }
  }
  __syncthreads();
  if (s_hist[tid]) gflags[tid] = 1;          // idempotent used-flags (512 entries)
}

__global__ __launch_bounds__(512) void vq_count(
    const int* __restrict__ gflags, float* __restrict__ out) {
  __shared__ int red[512];
  const int t = threadIdx.x;
  red[t] = (gflags[t] > 0) ? 1 : 0;
  __syncthreads();
  for (int s = 256; s > 0; s >>= 1) {
    if (t < s) red[t] += red[t + s];
    __syncthreads();
  }
  if (t == 0) out[OUT_SCALAR_IDX] = (float)red[0];
}

extern "C" void kernel_launch(void* const* d_in, const int* in_sizes, int n_in,
                              void* d_out, int out_size, void* d_ws, size_t ws_size,
                              hipStream_t stream) {
  const float* z = (const float*)d_in[0];
  const float* emb = (const float*)d_in[1];
  float* out = (float*)d_out;
  char* ws = (char*)d_ws;
  int* gflags = (int*)(ws + WS_GCOUNT);

  vq_prep<<<8, 64, 0, stream>>>(emb, ws);
  vq_mfma<<<NPOS / 256, 512, 0, stream>>>(z, emb, ws, out, gflags);
  vq_count<<<1, 512, 0, stream>>>(gflags, out);
}

// Round 10
// 39.277 us; speedup vs baseline: 1.1825x; 1.1642x over previous
//
#include <hip/hip_runtime.h>
#include <hip/hip_bf16.h>

#define NPOS (4*16*64*64)             // 262144 positions
#define KCODES 512
#define CDIM 64
#define OUT_SCALAR_IDX ((size_t)NPOS * CDIM)

// d_ws layout
#define WS_GCOUNT 0                   // 512 * int (used-flags)
#define WS_EMB    4096                // 32 KB: fp8(-512*e), kg-major: [kg][code][16B]
#define WS_EE     (4096 + 32768)      // 512 * float: 256*(1 + ||e||^2)

typedef float f32x4 __attribute__((ext_vector_type(4)));
typedef long lng2 __attribute__((ext_vector_type(2)));

// ---- prep: codebook -> kg-major fp8 image + biased/scaled ee + zero flags ----
__global__ __launch_bounds__(64) void vq_prep(
    const float* __restrict__ emb, char* __restrict__ ws) {
  const int r = blockIdx.x * 64 + threadIdx.x;     // 8 x 64 = 512 rows
  ((int*)(ws + WS_GCOUNT))[r] = 0;
  float c[CDIM];
  float ee = 0.f;
  #pragma unroll
  for (int q = 0; q < 16; ++q) {
    float4 x = ((const float4*)(emb + r * CDIM))[q];
    c[4*q+0] = x.x; c[4*q+1] = x.y; c[4*q+2] = x.z; c[4*q+3] = x.w;
    ee = fmaf(x.x, x.x, ee); ee = fmaf(x.y, x.y, ee);
    ee = fmaf(x.z, x.z, ee); ee = fmaf(x.w, x.w, ee);
  }
  #pragma unroll
  for (int kg = 0; kg < 4; ++kg) {
    uint u[4];
    #pragma unroll
    for (int h = 0; h < 2; ++h)
      #pragma unroll
      for (int jj = 0; jj < 2; ++jj) {
        const int kb = h * 32 + kg * 8 + jj * 4;
        uint p = __builtin_amdgcn_cvt_pk_fp8_f32(-512.f * c[kb+0], -512.f * c[kb+1], 0u, false);
        p = __builtin_amdgcn_cvt_pk_fp8_f32(-512.f * c[kb+2], -512.f * c[kb+3], p, true);
        u[h * 2 + jj] = p;
      }
    *(uint4*)(ws + WS_EMB + kg * 8192 + r * 16) = make_uint4(u[0], u[1], u[2], u[3]);
  }
  ((float*)(ws + WS_EE))[r] = 256.f * (1.f + ee);  // bias -> acc ~256, uint-monotone
}

__global__ __launch_bounds__(512, 4) void vq_mfma(
    const float* __restrict__ z, const float* __restrict__ emb,
    const char* __restrict__ ws, float* __restrict__ out,
    int* __restrict__ gflags) {
  __shared__ lng2 embs[2048];              // 32 KB fp8 image
  __shared__ float s_ee[KCODES];           // 2 KB
  __shared__ uint s_idx[512];              // 2 KB
  __shared__ int s_hist[KCODES];           // 2 KB

  const int tid = threadIdx.x;
  const int lane = tid & 63;
  const int w = tid >> 6;                  // 8 waves
  const int col = lane & 15;
  const int kg = lane >> 4;

  // ---- DMA first (oldest VMEM): image + ee -> LDS ----
  if (tid < 128)
    __builtin_amdgcn_global_load_lds(
        (const __attribute__((address_space(1))) void*)(ws + WS_EE + tid * 16),
        (__attribute__((address_space(3))) void*)((char*)s_ee + tid * 16), 16, 0, 0);
  const char* src = ws + WS_EMB;
  #pragma unroll
  for (int i = 0; i < 4; ++i) {
    const int off = (i * 512 + tid) * 16;
    __builtin_amdgcn_global_load_lds(
        (const __attribute__((address_space(1))) void*)(src + off),
        (__attribute__((address_space(3))) void*)((char*)embs + off), 16, 0, 0);
  }

  // ---- A loads: chunk0 then chunk1 (chunk1 stays in flight through hot0) ----
  const int nb = blockIdx.x * 512;               // 512 positions per block
  const int b = nb >> 16, spb = nb & 65535;      // single batch per block
  const float* zp0 = z + ((size_t)b << 22) + spb;
  const int pbase = w * 32 + col;                // within-chunk lane position

  float pf0[32], pf1[32];
  #pragma unroll
  for (int rt = 0; rt < 2; ++rt)
    #pragma unroll
    for (int h = 0; h < 2; ++h)
      #pragma unroll
      for (int j = 0; j < 8; ++j)
        pf0[rt*16 + h*8 + j] =
            zp0[pbase + rt*16 + ((size_t)(h*32 + kg*8 + j) << 16)];
  #pragma unroll
  for (int rt = 0; rt < 2; ++rt)
    #pragma unroll
    for (int h = 0; h < 2; ++h)
      #pragma unroll
      for (int j = 0; j < 8; ++j)
        pf1[rt*16 + h*8 + j] =
            zp0[256 + pbase + rt*16 + ((size_t)(h*32 + kg*8 + j) << 16)];

  // convert chunk0 (compiler inserts the value waits)
  long af0[2][2];
  #pragma unroll
  for (int rt = 0; rt < 2; ++rt)
    #pragma unroll
    for (int h = 0; h < 2; ++h) {
      const int o = rt*16 + h*8;
      uint u0 = __builtin_amdgcn_cvt_pk_fp8_f32(pf0[o+0], pf0[o+1], 0u, false);
      u0 = __builtin_amdgcn_cvt_pk_fp8_f32(pf0[o+2], pf0[o+3], u0, true);
      uint u1 = __builtin_amdgcn_cvt_pk_fp8_f32(pf0[o+4], pf0[o+5], 0u, false);
      u1 = __builtin_amdgcn_cvt_pk_fp8_f32(pf0[o+6], pf0[o+7], u1, true);
      af0[rt][h] = ((long)u1 << 32) | (long)u0;
    }
  s_hist[tid] = 0;

  // leave exactly chunk1's 32 loads outstanding -> DMA + chunk0 drained
  asm volatile("s_waitcnt vmcnt(32) lgkmcnt(0)" ::: "memory");
  __builtin_amdgcn_sched_barrier(0);
  __builtin_amdgcn_s_barrier();
  __builtin_amdgcn_sched_barrier(0);

  const int lbyte = kg * 8192 + col * 16;        // kg-major region base

#define CHUNK(AF, SBASE)                                                       \
  {                                                                            \
    uint key[2][4];                                                            \
    _Pragma("unroll") for (int rt = 0; rt < 2; ++rt)                           \
      _Pragma("unroll") for (int s = 0; s < 4; ++s) key[rt][s] = 0xFFFFFFFFu;  \
    lng2 bb = *(const lng2*)((const char*)embs + lbyte);                       \
    float eev = s_ee[col];                                                     \
    _Pragma("unroll 8")                                                        \
    for (int ct = 0; ct < 32; ++ct) {                                          \
      const lng2 bc = bb;                                                      \
      const float ec = eev;                                                    \
      const uint ctv = (uint)ct;                                               \
      const int nct = (ct + 1) & 31;                                           \
      bb = *(const lng2*)((const char*)embs + nct * 256 + lbyte);              \
      eev = s_ee[nct * 16 + col];                                              \
      const f32x4 cin = {ec, ec, ec, ec};                                      \
      _Pragma("unroll") for (int rt = 0; rt < 2; ++rt) {                       \
        f32x4 acc =                                                            \
            __builtin_amdgcn_mfma_f32_16x16x32_fp8_fp8(AF[rt][0], bc.x, cin, 0, 0, 0); \
        acc = __builtin_amdgcn_mfma_f32_16x16x32_fp8_fp8(AF[rt][1], bc.y, acc, 0, 0, 0); \
        _Pragma("unroll") for (int s = 0; s < 4; ++s) {                        \
          uint kb = (__builtin_bit_cast(uint, acc[s]) & 0xFFFFFFE0u) | ctv;    \
          key[rt][s] = kb < key[rt][s] ? kb : key[rt][s];                      \
        }                                                                      \
      }                                                                        \
    }                                                                          \
    _Pragma("unroll") for (int rt = 0; rt < 2; ++rt)                           \
      _Pragma("unroll") for (int s = 0; s < 4; ++s) {                          \
        uint k = (key[rt][s] << 4) | (uint)col;                                \
        _Pragma("unroll") for (int m = 1; m < 16; m <<= 1) {                   \
          uint o = (uint)__shfl_xor((int)k, m, 64);                            \
          k = o < k ? o : k;                                                   \
        }                                                                      \
        if (col == 0) s_idx[(SBASE) + w * 32 + rt * 16 + kg * 4 + s] = k;      \
      }                                                                        \
  }

  CHUNK(af0, 0)

  // convert chunk1 (loads had hot-loop0 to complete)
  long af1[2][2];
  #pragma unroll
  for (int rt = 0; rt < 2; ++rt)
    #pragma unroll
    for (int h = 0; h < 2; ++h) {
      const int o = rt*16 + h*8;
      uint u0 = __builtin_amdgcn_cvt_pk_fp8_f32(pf1[o+0], pf1[o+1], 0u, false);
      u0 = __builtin_amdgcn_cvt_pk_fp8_f32(pf1[o+2], pf1[o+3], u0, true);
      uint u1 = __builtin_amdgcn_cvt_pk_fp8_f32(pf1[o+4], pf1[o+5], 0u, false);
      u1 = __builtin_amdgcn_cvt_pk_fp8_f32(pf1[o+6], pf1[o+7], u1, true);
      af1[rt][h] = ((long)u1 << 32) | (long)u0;
    }

  CHUNK(af1, 256)

  __syncthreads();   // all 512 s_idx entries ready

  // ---- batched epilogue: 1 thread/position, 2KB write segments (R7 pattern) ----
  const uint kk = s_idx[tid];
  const int myidx = (int)(((kk >> 4) & 31u) * 16u + (kk & 15u));
  atomicAdd(&s_hist[myidx], 1);
  {
    const float4* ef = (const float4*)(emb + myidx * CDIM);
    float* o = out + ((size_t)b << 22) + spb + tid;
    #pragma unroll
    for (int q = 0; q < 16; ++q) {
      float4 e4 = ef[q];
      o[(size_t)(4 * q + 0) << 16] = e4.x;
      o[(size_t)(4 * q + 1) << 16] = e4.y;
      o[(size_t)(4 * q + 2) << 16] = e4.z;
      o[(size_t)(4 * q + 3) << 16] = e4.w;
    }
  }
  __syncthreads();
  if (s_hist[tid]) gflags[tid] = 1;          // idempotent used-flags
}

__global__ __launch_bounds__(512) void vq_count(
    const int* __restrict__ gflags, float* __restrict__ out) {
  __shared__ int red[512];
  const int t = threadIdx.x;
  red[t] = (gflags[t] > 0) ? 1 : 0;
  __syncthreads();
  for (int s = 256; s > 0; s >>= 1) {
    if (t < s) red[t] += red[t + s];
    __syncthreads();
  }
  if (t == 0) out[OUT_SCALAR_IDX] = (float)red[0];
}

extern "C" void kernel_launch(void* const* d_in, const int* in_sizes, int n_in,
                              void* d_out, int out_size, void* d_ws, size_t ws_size,
                              hipStream_t stream) {
  const float* z = (const float*)d_in[0];
  const float* emb = (const float*)d_in[1];
  float* out = (float*)d_out;
  char* ws = (char*)d_ws;
  int* gflags = (int*)(ws + WS_GCOUNT);

  vq_prep<<<8, 64, 0, stream>>>(emb, ws);
  vq_mfma<<<NPOS / 512, 512, 0, stream>>>(z, emb, ws, out, gflags);
  vq_count<<<1, 512, 0, stream>>>(gflags, out);
}